// Round 1
// baseline (180.023 us; speedup 1.0000x reference)
//
#include <hip/hip_runtime.h>

#define BN 131072   // B*N nodes
#define BE 2097152  // edges
#define NGR 64      // graphs
#define NPG 2048    // nodes per graph

// ws layout (element offsets in float units unless noted):
//   Xs     [64][16][64]  = 65536 f
//   wacc   [64][16]      = 1024 f
//   A_MM   [64][16][16]  = 16384 f
//   cnt    [64] int
//   cursor [64] int
//   start  [64] int
//   S      at byte 332800   (BN*16 f = 8,388,608 B)
//   packed at byte 8721408  (BE u32 = 8,388,608 B)
#define ZERO_BYTES (83136*4)
#define S_BYTE_OFF 332800
#define P_BYTE_OFF 8721408

// ---------------- node kernel: S = softmax(x@Wa+ba); accumulate Xs, w ----------
__global__ __launch_bounds__(128) void k_node(const float* __restrict__ x,
                                              const float* __restrict__ Wa,
                                              const float* __restrict__ ba,
                                              float* __restrict__ Sg,
                                              float* __restrict__ Xs,
                                              float* __restrict__ wacc)
{
    __shared__ float Xl[128 * 65];   // stride 65: (t + c) % 32 -> 2-way max, free
    __shared__ float Sl[128 * 17];
    __shared__ float Wl[64 * 16];

    const int t = threadIdx.x;
    const int blk = blockIdx.x;       // 1024 blocks, 128 nodes each
    const int g = blk >> 4;           // 16 blocks per graph

    // stage X tile (coalesced float4 global reads)
    const float4* xg4 = (const float4*)(x + (size_t)blk * 128 * 64);
    #pragma unroll
    for (int it = 0; it < 16; ++it) {
        int idx4 = it * 128 + t;
        float4 v = xg4[idx4];
        int node = idx4 >> 4;
        int c4 = (idx4 & 15) * 4;
        float* p = &Xl[node * 65 + c4];
        p[0] = v.x; p[1] = v.y; p[2] = v.z; p[3] = v.w;
    }
    for (int i = t; i < 1024; i += 128) Wl[i] = Wa[i];
    __syncthreads();

    // phase 1: per-thread node -> logits -> softmax
    float lg[16];
    #pragma unroll
    for (int m = 0; m < 16; ++m) lg[m] = ba[m];
    for (int c = 0; c < 64; ++c) {
        float xc = Xl[t * 65 + c];
        #pragma unroll
        for (int m = 0; m < 16; ++m) lg[m] += xc * Wl[c * 16 + m];
    }
    float mx = lg[0];
    #pragma unroll
    for (int m = 1; m < 16; ++m) mx = fmaxf(mx, lg[m]);
    float s[16]; float sum = 0.f;
    #pragma unroll
    for (int m = 0; m < 16; ++m) { s[m] = expf(lg[m] - mx); sum += s[m]; }
    float inv = 1.f / sum;
    #pragma unroll
    for (int m = 0; m < 16; ++m) s[m] *= inv;

    // store S (global, 4x float4 per node) + LDS
    float* srow = Sg + ((size_t)blk * 128 + t) * 16;
    #pragma unroll
    for (int q = 0; q < 4; ++q) {
        float4 v4 = make_float4(s[q*4], s[q*4+1], s[q*4+2], s[q*4+3]);
        *(float4*)(srow + q * 4) = v4;
    }
    #pragma unroll
    for (int m = 0; m < 16; ++m) Sl[t * 17 + m] = s[m];
    __syncthreads();

    // phase 2: Xs[m][c] = sum_n S[n][m] * X[n][c]; thread owns (c, 8 m's)
    const int c = t & 63;
    const int half = t >> 6;
    float acc[8];
    #pragma unroll
    for (int j = 0; j < 8; ++j) acc[j] = 0.f;
    for (int n = 0; n < 128; ++n) {
        float xv = Xl[n * 65 + c];
        #pragma unroll
        for (int j = 0; j < 8; ++j) acc[j] += Sl[n * 17 + half * 8 + j] * xv;
    }
    float* xsg = Xs + g * 1024;
    #pragma unroll
    for (int j = 0; j < 8; ++j) atomicAdd(&xsg[(half * 8 + j) * 64 + c], acc[j]);

    if (t < 16) {
        float ws_ = 0.f;
        for (int n = 0; n < 128; ++n) ws_ += Sl[n * 17 + t];
        atomicAdd(&wacc[g * 16 + t], ws_);
    }
}

// ---------------- edge histogram by source graph ----------------
__global__ __launch_bounds__(256) void k_hist(const int* __restrict__ e0, int* __restrict__ cnt)
{
    __shared__ int h[64];
    int t = threadIdx.x;
    if (t < 64) h[t] = 0;
    __syncthreads();
    size_t base = (size_t)blockIdx.x * 4096;
    #pragma unroll
    for (int k = 0; k < 16; ++k) {
        int e = e0[base + k * 256 + t];
        atomicAdd(&h[e >> 11], 1);
    }
    __syncthreads();
    if (t < 64) atomicAdd(&cnt[t], h[t]);
}

__global__ void k_prefix(const int* __restrict__ cnt, int* __restrict__ start, int* __restrict__ cursor)
{
    if (threadIdx.x == 0) {
        int ssum = 0;
        for (int g = 0; g < 64; ++g) { start[g] = ssum; cursor[g] = ssum; ssum += cnt[g]; }
    }
}

// ---------------- scatter edges grouped by graph, packed (e0local<<17 | e1) ----
__global__ __launch_bounds__(256) void k_scatter(const int* __restrict__ e_,
                                                 int* __restrict__ cursor,
                                                 unsigned* __restrict__ packed)
{
    __shared__ int h[64];
    __shared__ int gb[64];
    int t = threadIdx.x;
    if (t < 64) h[t] = 0;
    __syncthreads();
    size_t base = (size_t)blockIdx.x * 4096;
    int e0v[16], e1v[16], rk[16];
    #pragma unroll
    for (int k = 0; k < 16; ++k) {
        size_t i = base + k * 256 + t;
        e0v[k] = e_[i];
        e1v[k] = e_[BE + i];
        rk[k] = atomicAdd(&h[e0v[k] >> 11], 1);
    }
    __syncthreads();
    if (t < 64) gb[t] = atomicAdd(&cursor[t], h[t]);
    __syncthreads();
    #pragma unroll
    for (int k = 0; k < 16; ++k) {
        int b = e0v[k] >> 11;
        packed[gb[b] + rk[k]] = ((unsigned)(e0v[k] & 2047) << 17) | (unsigned)e1v[k];
    }
}

// ---------------- edge kernel: A_MM[g] += outer(S[e0], S[e1]) ------------------
#define EDGE_BODY(u)                                                     \
    {                                                                    \
        int e1 = (int)((u) & 131071u);                                   \
        int e0l = (int)((u) >> 17);                                      \
        float s0 = Sg[((gbase + e0l) << 4) + m];                         \
        float4 s1 = *(const float4*)(Sg + e1 * 16 + kq4);                \
        a0 += s0 * s1.x; a1 += s0 * s1.y; a2 += s0 * s1.z; a3 += s0 * s1.w; \
    }

__global__ __launch_bounds__(256) void k_edge(const unsigned* __restrict__ packed,
                                              const float* __restrict__ Sg,
                                              const int* __restrict__ start,
                                              const int* __restrict__ cnt,
                                              float* __restrict__ A)
{
    const int t = threadIdx.x;
    const int lane = t & 63;
    const int g = blockIdx.x >> 4;
    const int Wv = ((blockIdx.x & 15) << 2) + (t >> 6);   // wave id within graph, 0..63
    const int est = start[g];
    const int n = cnt[g];
    const int m = lane & 15;
    const int kq4 = (lane >> 4) << 2;
    const int gbase = g << 11;

    float a0 = 0.f, a1 = 0.f, a2 = 0.f, a3 = 0.f;

    for (int base = Wv * 64; base < n; base += 64 * 64) {
        int count = min(64, n - base);
        unsigned pk = packed[est + base + min(lane, count - 1)];
        if (count == 64) {
            #pragma unroll 8
            for (int i = 0; i < 64; ++i) {
                unsigned u = (unsigned)__shfl((int)pk, i);
                EDGE_BODY(u)
            }
        } else {
            for (int i = 0; i < count; ++i) {
                unsigned u = (unsigned)__shfl((int)pk, i);
                EDGE_BODY(u)
            }
        }
    }
    float* Ag = A + g * 256 + m * 16 + kq4;
    atomicAdd(&Ag[0], a0);
    atomicAdd(&Ag[1], a1);
    atomicAdd(&Ag[2], a2);
    atomicAdd(&Ag[3], a3);
}

// ---------------- x_out: [Zp(3) | Zf(61)] per (g,m) row ------------------------
__global__ __launch_bounds__(256) void k_xout(const float* __restrict__ Xs,
                                              const float* __restrict__ wacc,
                                              const float* __restrict__ We,
                                              const float* __restrict__ be,
                                              float* __restrict__ out)
{
    int t = threadIdx.x;
    int lane = t & 63;
    int row = blockIdx.x * 4 + (t >> 6);  // 0..1023
    const float* xs = Xs + row * 64;
    float w = wacc[row];
    float val;
    if (lane < 3) {
        val = xs[lane] / fmaxf(w, 1e-10f);
    } else {
        int c2 = lane - 3;
        float accv = w * be[c2];
        for (int cc = 0; cc < 64; ++cc) accv += xs[cc] * We[cc * 61 + c2];
        val = accv;
    }
    out[row * 64 + lane] = val;
}

// ---------------- top-k(4) of A_MM rows -> e_out, b_out ------------------------
__global__ __launch_bounds__(256) void k_topk(const float* __restrict__ A, float* __restrict__ out)
{
    int r = blockIdx.x * 256 + threadIdx.x;   // 0..1023  (= g*16 + m)
    float v[16];
    #pragma unroll
    for (int i = 0; i < 16; ++i) v[i] = A[r * 16 + i];
    float* e0o = out + 65536;
    float* e1o = out + 65536 + 4096;
    float* bo  = out + 65536 + 8192;
    unsigned mask = 0;
    #pragma unroll
    for (int rep = 0; rep < 4; ++rep) {
        float best = -3.4e38f; int bi = 0;
        #pragma unroll
        for (int i = 0; i < 16; ++i) {
            bool ok = (((mask >> i) & 1u) == 0u) && (v[i] > best);
            if (ok) { best = v[i]; bi = i; }
        }
        mask |= (1u << bi);
        e0o[r * 4 + rep] = (float)r;                       // src + offset == row index
        e1o[r * 4 + rep] = (float)((r & ~15) + bi);        // dst + g*16
    }
    bo[r] = (float)(r >> 4);
}

extern "C" void kernel_launch(void* const* d_in, const int* in_sizes, int n_in,
                              void* d_out, int out_size, void* d_ws, size_t ws_size,
                              hipStream_t stream)
{
    const float* x  = (const float*)d_in[0];
    const int*   e  = (const int*)d_in[1];
    const float* Wa = (const float*)d_in[3];
    const float* ba = (const float*)d_in[4];
    const float* We = (const float*)d_in[5];
    const float* be = (const float*)d_in[6];

    char* ws = (char*)d_ws;
    float* Xs     = (float*)ws;
    float* wacc   = Xs + 65536;
    float* A      = wacc + 1024;
    int*   cnt    = (int*)(A + 16384);
    int*   cursor = cnt + 64;
    int*   start  = cursor + 64;
    float* Sg     = (float*)(ws + S_BYTE_OFF);
    unsigned* packed = (unsigned*)(ws + P_BYTE_OFF);

    hipMemsetAsync(ws, 0, ZERO_BYTES, stream);
    k_node   <<<1024, 128, 0, stream>>>(x, Wa, ba, Sg, Xs, wacc);
    k_hist   <<<512, 256, 0, stream>>>(e, cnt);
    k_prefix <<<1, 64, 0, stream>>>(cnt, start, cursor);
    k_scatter<<<512, 256, 0, stream>>>(e, cursor, packed);
    k_edge   <<<1024, 256, 0, stream>>>(packed, Sg, start, cnt, A);
    k_xout   <<<256, 256, 0, stream>>>(Xs, wacc, We, be, (float*)d_out);
    k_topk   <<<4, 256, 0, stream>>>(A, (float*)d_out);
}